// Round 7
// baseline (1013.950 us; speedup 1.0000x reference)
//
#include <hip/hip_runtime.h>
#include <hip/hip_bf16.h>
#include <cstdint>

#define NEG_SLOPE 0.2f

typedef __attribute__((ext_vector_type(8))) short bf16x8;
typedef __attribute__((ext_vector_type(4))) float f32x4;

// ---------- bf16 helpers (manual RNE, bit-level) ----------
__device__ __forceinline__ unsigned short f2bf(float f) {
    unsigned u = __float_as_uint(f);
    unsigned r = (u + 0x7FFFu + ((u >> 16) & 1u)) >> 16;
    return (unsigned short)r;
}
__device__ __forceinline__ float bf2f(unsigned short h) {
    return __uint_as_float(((unsigned)h) << 16);
}
__device__ __forceinline__ void splitbf(float v, unsigned short& hi, unsigned short& lo) {
    hi = f2bf(v);
    lo = f2bf(v - bf2f(hi));
}

// 16-byte load that only assumes 4-byte alignment (rows with odd K, e.g. 773)
struct __attribute__((packed, aligned(4))) F4A4 { float x, y, z, w; };
__device__ __forceinline__ float4 load4_a4(const float* p) {
    F4A4 v = *reinterpret_cast<const F4A4*>(p);
    return make_float4(v.x, v.y, v.z, v.w);
}

// ---------- weight prep: W [K][M] fp32 -> Bt_hi/Bt_lo [M][Kp] bf16 (transposed, padded) ----------
__global__ __launch_bounds__(256) void convertB(
    const float* __restrict__ W, unsigned short* __restrict__ bth,
    unsigned short* __restrict__ btl, int K, int M, int Kp)
{
    int idx = blockIdx.x * 256 + threadIdx.x;
    if (idx >= M * Kp) return;
    int m = idx / Kp, k = idx % Kp;
    float v = (k < K) ? W[(size_t)k * M + m] : 0.0f;
    unsigned short h, l;
    splitbf(v, h, l);
    bth[idx] = h; btl[idx] = l;
}

// ---------- split-bf16 MFMA GEMM ----------
// APLANES=0: A fp32 [N][K], split in-kernel.  APLANES=1: A pre-split planes [N][Kp] bf16.
// 128x128 tile, 4 waves (2x2), 16x16x32 bf16 MFMA, 3 pairings (hh + lh + hl).
// 2-phase register prefetch; XOR 16B-chunk LDS swizzle (measured conflict-free).
// Epilogue: optional fp32 C and/or pre-split hi/lo bf16 planes (feeds next GEMM).
#define BM 128
#define BN 128
#define BK 32
__device__ __forceinline__ int swz(int r, int c) { return c ^ ((r >> 1) & 3); }

template <int APLANES>
__global__ __launch_bounds__(256, 2) void gemm_mfma(
    const float* __restrict__ Af, const unsigned short* __restrict__ Aph,
    const unsigned short* __restrict__ Apl,
    const unsigned short* __restrict__ Bth, const unsigned short* __restrict__ Btl,
    const float* __restrict__ bias, float* __restrict__ Cf,
    unsigned short* __restrict__ Ch, unsigned short* __restrict__ Cl,
    int N, int K, int Kp, int M, int dobias)
{
    __shared__ unsigned short sAh[BM][BK], sAl[BM][BK];
    __shared__ unsigned short sBh[BN][BK], sBl[BN][BK];
    const int tid = threadIdx.x;
    const int lane = tid & 63;
    const int wid = tid >> 6;
    const int wm = wid >> 1, wn = wid & 1;
    const int row0 = blockIdx.y * BM, col0 = blockIdx.x * BN;
    const int nt = Kp / BK;

    f32x4 acc[4][4];
    #pragma unroll
    for (int i = 0; i < 4; ++i)
        #pragma unroll
        for (int j = 0; j < 4; ++j)
            acc[i][j] = (f32x4)0.0f;

    float4 ra[4];            // APLANES==0
    uint4 rah[2], ral[2];    // APLANES==1
    uint4 rbh[2], rbl[2];

    auto loadA = [&](int k0) {
        if constexpr (APLANES == 0) {
            #pragma unroll
            for (int i = 0; i < 4; ++i) {
                int flat = i * 256 + tid;
                int r = flat >> 3, ch = flat & 7;
                int gr = row0 + r, gk = k0 + ch * 4;
                float4 v = make_float4(0.f, 0.f, 0.f, 0.f);
                if (gr < N) {
                    const float* ap = Af + (size_t)gr * K + gk;
                    if (gk + 3 < K) {
                        v = load4_a4(ap);
                    } else {
                        if (gk + 0 < K) v.x = ap[0];
                        if (gk + 1 < K) v.y = ap[1];
                        if (gk + 2 < K) v.z = ap[2];
                        if (gk + 3 < K) v.w = ap[3];
                    }
                }
                ra[i] = v;
            }
        } else {
            #pragma unroll
            for (int i = 0; i < 2; ++i) {
                int flat = i * 256 + tid;
                int r = flat >> 2, ch = flat & 3;
                int gr = row0 + r;
                if (gr < N) {
                    size_t off = (size_t)gr * Kp + k0 + ch * 8;
                    rah[i] = *reinterpret_cast<const uint4*>(Aph + off);
                    ral[i] = *reinterpret_cast<const uint4*>(Apl + off);
                } else {
                    rah[i] = make_uint4(0, 0, 0, 0);
                    ral[i] = make_uint4(0, 0, 0, 0);
                }
            }
        }
    };
    auto loadB = [&](int k0) {
        #pragma unroll
        for (int i = 0; i < 2; ++i) {
            int flat = i * 256 + tid;
            int r = flat >> 2, ch = flat & 3;
            size_t goff = (size_t)(col0 + r) * Kp + k0 + ch * 8;
            rbh[i] = *reinterpret_cast<const uint4*>(Bth + goff);
            rbl[i] = *reinterpret_cast<const uint4*>(Btl + goff);
        }
    };

    loadA(0); loadB(0);

    for (int kt = 0; kt < nt; ++kt) {
        // ---- prefetched regs -> LDS ----
        if constexpr (APLANES == 0) {
            #pragma unroll
            for (int i = 0; i < 4; ++i) {
                int flat = i * 256 + tid;
                int r = flat >> 3, ch = flat & 7;
                unsigned short h0, h1, h2, h3, l0, l1, l2, l3;
                splitbf(ra[i].x, h0, l0); splitbf(ra[i].y, h1, l1);
                splitbf(ra[i].z, h2, l2); splitbf(ra[i].w, h3, l3);
                int cu = swz(r, ch >> 1) * 8 + (ch & 1) * 4;
                *reinterpret_cast<ushort4*>(&sAh[r][cu]) = make_ushort4(h0, h1, h2, h3);
                *reinterpret_cast<ushort4*>(&sAl[r][cu]) = make_ushort4(l0, l1, l2, l3);
            }
        } else {
            #pragma unroll
            for (int i = 0; i < 2; ++i) {
                int flat = i * 256 + tid;
                int r = flat >> 2, ch = flat & 3;
                int cu = swz(r, ch) * 8;
                *reinterpret_cast<uint4*>(&sAh[r][cu]) = rah[i];
                *reinterpret_cast<uint4*>(&sAl[r][cu]) = ral[i];
            }
        }
        #pragma unroll
        for (int i = 0; i < 2; ++i) {
            int flat = i * 256 + tid;
            int r = flat >> 2, ch = flat & 3;
            int cu = swz(r, ch) * 8;
            *reinterpret_cast<uint4*>(&sBh[r][cu]) = rbh[i];
            *reinterpret_cast<uint4*>(&sBl[r][cu]) = rbl[i];
        }
        __syncthreads();

        // ---- issue next tile's global loads (overlap with MFMA below) ----
        if (kt + 1 < nt) { loadA((kt + 1) * BK); loadB((kt + 1) * BK); }

        // ---- frags + MFMA from LDS ----
        const int g = lane >> 4;
        const int rA0 = wm * 64 + (lane & 15);
        const int rB0 = wn * 64 + (lane & 15);
        bf16x8 ah[4], al[4];
        #pragma unroll
        for (int m = 0; m < 4; ++m) {
            int rr = rA0 + m * 16;
            int cu = swz(rr, g) * 8;
            ah[m] = *reinterpret_cast<const bf16x8*>(&sAh[rr][cu]);
            al[m] = *reinterpret_cast<const bf16x8*>(&sAl[rr][cu]);
        }
        #pragma unroll
        for (int n = 0; n < 4; ++n) {
            int rr = rB0 + n * 16;
            int cu = swz(rr, g) * 8;
            bf16x8 bh = *reinterpret_cast<const bf16x8*>(&sBh[rr][cu]);
            bf16x8 bl = *reinterpret_cast<const bf16x8*>(&sBl[rr][cu]);
            #pragma unroll
            for (int m = 0; m < 4; ++m) {
                acc[m][n] = __builtin_amdgcn_mfma_f32_16x16x32_bf16(ah[m], bh, acc[m][n], 0, 0, 0);
                acc[m][n] = __builtin_amdgcn_mfma_f32_16x16x32_bf16(al[m], bh, acc[m][n], 0, 0, 0);
                acc[m][n] = __builtin_amdgcn_mfma_f32_16x16x32_bf16(ah[m], bl, acc[m][n], 0, 0, 0);
            }
        }
        __syncthreads();
    }

    // ---- C write: D layout col=lane&15, row=(lane>>4)*4+reg ----
    #pragma unroll
    for (int m = 0; m < 4; ++m) {
        #pragma unroll
        for (int n = 0; n < 4; ++n) {
            int col = col0 + wn * 64 + n * 16 + (lane & 15);
            #pragma unroll
            for (int r = 0; r < 4; ++r) {
                int row = row0 + wm * 64 + m * 16 + (lane >> 4) * 4 + r;
                if (row < N) {
                    float v = acc[m][n][r];
                    if (dobias) v = fmaxf(v + bias[col], 0.0f);
                    size_t o = (size_t)row * M + col;
                    if (Cf) Cf[o] = v;
                    if (Ch) {
                        unsigned short h, l;
                        splitbf(v, h, l);
                        Ch[o] = h; Cl[o] = l;
                    }
                }
            }
        }
    }
}

// ---------- per-node attention coefficients: a_src[n,h], a_dst[n,h] ----------
template <int F>   // F = H*C, H=4; one wave per node
__global__ __launch_bounds__(256) void attn_coeff(
    const float* __restrict__ h, const float* __restrict__ att_src,
    const float* __restrict__ att_dst, float* __restrict__ a_src,
    float* __restrict__ a_dst, int N)
{
    constexpr int VPT = F / 64;
    constexpr int C = F / 4;
    int wave = (blockIdx.x * blockDim.x + threadIdx.x) >> 6;
    int lane = threadIdx.x & 63;
    if (wave >= N) return;
    int j0 = lane * VPT;
    int hd = j0 / C;
    float ps = 0.f, pd = 0.f;
    #pragma unroll
    for (int t = 0; t < VPT; ++t) {
        int j = j0 + t;
        float v = h[(size_t)wave * F + j];
        int c = j - hd * C;
        ps += v * att_src[hd * C + c];
        pd += v * att_dst[hd * C + c];
    }
    #pragma unroll
    for (int off = 8; off >= 1; off >>= 1) {
        ps += __shfl_xor(ps, off, 64);
        pd += __shfl_xor(pd, off, 64);
    }
    if ((lane & 15) == 0) {
        a_src[wave * 4 + hd] = ps;
        a_dst[wave * 4 + hd] = pd;
    }
}

// ---------- CSR build: histogram ----------
__global__ __launch_bounds__(256) void hist_kernel(
    const int* __restrict__ ei, int* __restrict__ counts, int E, int Etot)
{
    int i = blockIdx.x * blockDim.x + threadIdx.x;
    if (i >= Etot) return;
    int d = (i < E) ? ei[E + i] : (i - E);
    atomicAdd(&counts[d], 1);
}

// ---------- CSR build: 3-stage exclusive scan -> row_ptr ----------
__global__ __launch_bounds__(256) void scan1_kernel(
    const int* __restrict__ counts, int* __restrict__ row_ptr,
    int* __restrict__ partials, int N)
{
    __shared__ int sh[256];
    int tid = threadIdx.x;
    int i = blockIdx.x * 256 + tid;
    int v = (i < N) ? counts[i] : 0;
    sh[tid] = v;
    __syncthreads();
    #pragma unroll
    for (int off = 1; off < 256; off <<= 1) {
        int t = (tid >= off) ? sh[tid - off] : 0;
        __syncthreads();
        sh[tid] += t;
        __syncthreads();
    }
    if (i < N) row_ptr[i + 1] = sh[tid];
    if (tid == 255) partials[blockIdx.x] = sh[255];
}

__global__ __launch_bounds__(256) void scan2_kernel(int* __restrict__ partials, int nb)
{
    __shared__ int sh[256];
    int tid = threadIdx.x;
    int v = (tid < nb) ? partials[tid] : 0;
    sh[tid] = v;
    __syncthreads();
    #pragma unroll
    for (int off = 1; off < 256; off <<= 1) {
        int t = (tid >= off) ? sh[tid - off] : 0;
        __syncthreads();
        sh[tid] += t;
        __syncthreads();
    }
    if (tid < nb) partials[tid] = sh[tid] - v;
}

__global__ __launch_bounds__(256) void scan3_kernel(
    int* __restrict__ row_ptr, const int* __restrict__ partials, int N)
{
    int i = blockIdx.x * 256 + threadIdx.x;
    if (i == 0) row_ptr[0] = 0;
    if (i < N) row_ptr[i + 1] += partials[i >> 8];
}

// ---------- CSR build: fill column (src) list ----------
__global__ __launch_bounds__(256) void fill_kernel(
    const int* __restrict__ ei, int* __restrict__ cursor,
    int* __restrict__ col, int E, int Etot)
{
    int i = blockIdx.x * blockDim.x + threadIdx.x;
    if (i >= Etot) return;
    int s, d;
    if (i < E) { s = ei[i]; d = ei[E + i]; } else { s = i - E; d = s; }
    int slot = atomicAdd(&cursor[d], 1);
    col[slot] = s;
}

// ---------- fused per-dst GAT aggregation: softmax + gather + bias + relu ----------
// Output: fp32 (outF) or pre-split hi/lo planes (outH/outL) for the next GEMM.
template <int F>   // one wave per destination node; C = F/4 per head
__global__ __launch_bounds__(256) void gat_aggregate(
    const int* __restrict__ row_ptr, const int* __restrict__ col,
    const float* __restrict__ h, const float* __restrict__ a_src,
    const float* __restrict__ a_dst, const float* __restrict__ bias,
    float* __restrict__ outF, unsigned short* __restrict__ outH,
    unsigned short* __restrict__ outL, int N)
{
    constexpr int VPT = F / 64;
    int wave = (blockIdx.x * blockDim.x + threadIdx.x) >> 6;
    int lane = threadIdx.x & 63;
    if (wave >= N) return;
    const int d = wave;
    const int start = row_ptr[d], end = row_ptr[d + 1];

    float4 adv = *reinterpret_cast<const float4*>(&a_dst[d * 4]);
    const float ad[4] = {adv.x, adv.y, adv.z, adv.w};

    float m[4] = {-1e30f, -1e30f, -1e30f, -1e30f};
    for (int j = start + lane; j < end; j += 64) {
        int s = col[j];
        float4 asv = *reinterpret_cast<const float4*>(&a_src[s * 4]);
        float ev[4] = {asv.x + ad[0], asv.y + ad[1], asv.z + ad[2], asv.w + ad[3]};
        #pragma unroll
        for (int hd = 0; hd < 4; ++hd) {
            float e = ev[hd];
            e = (e >= 0.f) ? e : NEG_SLOPE * e;
            m[hd] = fmaxf(m[hd], e);
        }
    }
    #pragma unroll
    for (int off = 32; off >= 1; off >>= 1) {
        #pragma unroll
        for (int hd = 0; hd < 4; ++hd)
            m[hd] = fmaxf(m[hd], __shfl_xor(m[hd], off, 64));
    }

    float den[4] = {0.f, 0.f, 0.f, 0.f};
    for (int j = start + lane; j < end; j += 64) {
        int s = col[j];
        float4 asv = *reinterpret_cast<const float4*>(&a_src[s * 4]);
        float ev[4] = {asv.x + ad[0], asv.y + ad[1], asv.z + ad[2], asv.w + ad[3]};
        #pragma unroll
        for (int hd = 0; hd < 4; ++hd) {
            float e = ev[hd];
            e = (e >= 0.f) ? e : NEG_SLOPE * e;
            den[hd] += __expf(e - m[hd]);
        }
    }
    #pragma unroll
    for (int off = 32; off >= 1; off >>= 1) {
        #pragma unroll
        for (int hd = 0; hd < 4; ++hd)
            den[hd] += __shfl_xor(den[hd], off, 64);
    }

    const int hd_l = lane >> 4;
    const float mm = m[hd_l];
    const float iv = 1.0f / (den[hd_l] + 1e-16f);
    const float adh = ad[hd_l];
    float acc[VPT] = {};
    for (int j = start; j < end; ++j) {
        int s = col[j];
        float e = a_src[s * 4 + hd_l] + adh;
        e = (e >= 0.f) ? e : NEG_SLOPE * e;
        float alpha = __expf(e - mm) * iv;
        if constexpr (VPT == 4) {
            float4 hv = *reinterpret_cast<const float4*>(&h[(size_t)s * F + lane * 4]);
            acc[0] += hv.x * alpha; acc[1] += hv.y * alpha;
            acc[2] += hv.z * alpha; acc[3] += hv.w * alpha;
        } else {
            float2 hv = *reinterpret_cast<const float2*>(&h[(size_t)s * F + lane * 2]);
            acc[0] += hv.x * alpha; acc[1] += hv.y * alpha;
        }
    }
    #pragma unroll
    for (int t = 0; t < VPT; ++t) {
        int j = lane * VPT + t;
        float v = fmaxf(acc[t] + bias[j], 0.0f);
        size_t o = (size_t)d * F + j;
        if (outF) {
            outF[o] = v;
        } else {
            unsigned short hh, ll;
            splitbf(v, hh, ll);
            outH[o] = hh; outL[o] = ll;
        }
    }
}

// ---------- mean pool: batch is SORTED -> register accumulate, flush on graph change ----------
#define POOL_RPW 64
__global__ __launch_bounds__(256) void pool_kernel(
    const float* __restrict__ h2, const int* __restrict__ batch,
    float* __restrict__ pooled, float* __restrict__ counts, int N)
{
    int wave = (blockIdx.x * blockDim.x + threadIdx.x) >> 6;
    int lane = threadIdx.x & 63;
    int r0 = wave * POOL_RPW;
    if (r0 >= N) return;
    int r1 = min(r0 + POOL_RPW, N);
    int cur_g = batch[r0];
    float a0 = 0.f, a1 = 0.f, cnt = 0.f;
    for (int r = r0; r < r1; ++r) {
        int g = batch[r];
        if (g != cur_g) {
            atomicAdd(&pooled[cur_g * 128 + lane * 2 + 0], a0);
            atomicAdd(&pooled[cur_g * 128 + lane * 2 + 1], a1);
            if (lane == 0) atomicAdd(&counts[cur_g], cnt);
            a0 = a1 = cnt = 0.f;
            cur_g = g;
        }
        float2 hv = *reinterpret_cast<const float2*>(&h2[(size_t)r * 128 + lane * 2]);
        a0 += hv.x; a1 += hv.y; cnt += 1.f;
    }
    atomicAdd(&pooled[cur_g * 128 + lane * 2 + 0], a0);
    atomicAdd(&pooled[cur_g * 128 + lane * 2 + 1], a1);
    if (lane == 0) atomicAdd(&counts[cur_g], cnt);
}

// ---------- classifier head: one wave per graph ----------
__global__ __launch_bounds__(256) void head_kernel(
    const float* __restrict__ pooled, const float* __restrict__ counts,
    const float* __restrict__ Wc, const float* __restrict__ bc,
    const float* __restrict__ Wf, const float* __restrict__ bf,
    float* __restrict__ out)
{
    int wave = (blockIdx.x * blockDim.x + threadIdx.x) >> 6;
    int lane = threadIdx.x & 63;
    if (wave >= 64) return;
    float inv = 1.0f / fmaxf(counts[wave], 1.0f);
    float p0 = pooled[wave * 128 + lane] * inv;
    float p1 = pooled[wave * 128 + 64 + lane] * inv;
    float a0 = p0 * Wc[lane * 2 + 0] + p1 * Wc[(lane + 64) * 2 + 0];
    float a1 = p0 * Wc[lane * 2 + 1] + p1 * Wc[(lane + 64) * 2 + 1];
    float ac = p0 * Wf[lane] + p1 * Wf[lane + 64];
    #pragma unroll
    for (int off = 32; off >= 1; off >>= 1) {
        a0 += __shfl_xor(a0, off, 64);
        a1 += __shfl_xor(a1, off, 64);
        ac += __shfl_xor(ac, off, 64);
    }
    if (lane == 0) {
        out[wave * 2 + 0] = a0 + bc[0];
        out[wave * 2 + 1] = a1 + bc[1];
        out[128 + wave] = 1.0f / (1.0f + __expf(-(ac + bf[0])));
    }
}

extern "C" void kernel_launch(void* const* d_in, const int* in_sizes, int n_in,
                              void* d_out, int out_size, void* d_ws, size_t ws_size,
                              hipStream_t stream)
{
    const float* x     = (const float*)d_in[0];
    const int*   ei    = (const int*)d_in[1];
    const int*   batch = (const int*)d_in[2];
    const float* W_in  = (const float*)d_in[3];
    const float* b_in  = (const float*)d_in[4];
    const float* W1    = (const float*)d_in[5];
    const float* as1   = (const float*)d_in[6];
    const float* ad1   = (const float*)d_in[7];
    const float* bias1 = (const float*)d_in[8];
    const float* W2    = (const float*)d_in[9];
    const float* as2   = (const float*)d_in[10];
    const float* ad2   = (const float*)d_in[11];
    const float* bias2 = (const float*)d_in[12];
    const float* Wc    = (const float*)d_in[13];
    const float* bc    = (const float*)d_in[14];
    const float* Wf    = (const float*)d_in[15];
    const float* bf    = (const float*)d_in[16];
    float* out = (float*)d_out;

    const int N    = in_sizes[2];          // 50000
    const int E    = in_sizes[1] / 2;      // 800000
    const int K0   = in_sizes[0] / N;      // 773
    const int Etot = E + N;
    const int HID = 256, OUTF = 128;
    const int Kp0 = ((K0 + 31) / 32) * 32; // 800
    const int nb  = (N + 255) / 256;

    char* ws = (char*)d_ws;
    size_t off = 0;
    auto alloc = [&](size_t bytes) -> void* {
        void* p = ws + off;
        off = (off + bytes + 255) & ~(size_t)255;
        return p;
    };
    // P0: h0 hi/lo planes (layer-1 GEMM input), later reused for h1 planes
    unsigned short* P0 = (unsigned short*)alloc((size_t)N * HID * 2 * 2);
    // P1: hc1 fp32, later hc2 + out2
    float* P1      = (float*)alloc((size_t)N * HID * 4);
    float* a_src   = (float*)alloc((size_t)N * 4 * 4);
    float* a_dst   = (float*)alloc((size_t)N * 4 * 4);
    int*   counts  = (int*)alloc((size_t)(N + 1) * 4);
    int*   row_ptr = (int*)alloc((size_t)(N + 1) * 4);
    int*   cursor  = (int*)alloc((size_t)N * 4);
    int*   colv    = (int*)alloc((size_t)Etot * 4);
    int*   partials= (int*)alloc(256 * 4);
    float* pooled  = (float*)alloc(64 * 128 * 4);
    float* gcounts = (float*)alloc(64 * 4);
    unsigned short* Bth0 = (unsigned short*)alloc((size_t)HID * Kp0 * 2);
    unsigned short* Btl0 = (unsigned short*)alloc((size_t)HID * Kp0 * 2);
    unsigned short* Bth1 = (unsigned short*)alloc((size_t)HID * HID * 2);
    unsigned short* Btl1 = (unsigned short*)alloc((size_t)HID * HID * 2);
    unsigned short* Bth2 = (unsigned short*)alloc((size_t)OUTF * HID * 2);
    unsigned short* Btl2 = (unsigned short*)alloc((size_t)OUTF * HID * 2);
    (void)ws_size; (void)n_in; (void)out_size;

    unsigned short* h0h = P0;
    unsigned short* h0l = P0 + (size_t)N * HID;
    unsigned short* h1h = P0;                       // reuse after gemm2
    unsigned short* h1l = P0 + (size_t)N * HID;
    float* hc1  = P1;
    float* hc2  = P1;                               // reuse after agg1
    float* out2 = P1 + (size_t)N * OUTF;

    dim3 blk(256);
    dim3 gEdge((Etot + 255) / 256);
    dim3 gNodeWave((N + 3) / 4);
    dim3 gNodeTh((N + 255) / 256);
    dim3 gPool(((N + POOL_RPW - 1) / POOL_RPW + 3) / 4);
    const int gRows = (N + BM - 1) / BM;

    // ---- weight split/transpose (tiny) ----
    convertB<<<dim3((HID * Kp0 + 255) / 256), blk, 0, stream>>>(W_in, Bth0, Btl0, K0, HID, Kp0);
    convertB<<<dim3((HID * HID + 255) / 256), blk, 0, stream>>>(W1, Bth1, Btl1, HID, HID, HID);
    convertB<<<dim3((OUTF * HID + 255) / 256), blk, 0, stream>>>(W2, Bth2, Btl2, HID, OUTF, HID);

    // ---- CSR build (reused by both GAT layers) ----
    hipMemsetAsync(counts, 0, (size_t)(N + 1) * 4, stream);
    hist_kernel<<<gEdge, blk, 0, stream>>>(ei, counts, E, Etot);
    scan1_kernel<<<dim3(nb), blk, 0, stream>>>(counts, row_ptr, partials, N);
    scan2_kernel<<<dim3(1), blk, 0, stream>>>(partials, nb);
    scan3_kernel<<<gNodeTh, blk, 0, stream>>>(row_ptr, partials, N);
    hipMemcpyAsync(cursor, row_ptr, (size_t)N * 4, hipMemcpyDeviceToDevice, stream);
    fill_kernel<<<gEdge, blk, 0, stream>>>(ei, cursor, colv, E, Etot);

    // ---- input projection: h0 = relu(x @ W_in + b_in), emitted as split planes ----
    gemm_mfma<0><<<dim3(HID / BN, gRows), blk, 0, stream>>>(
        x, nullptr, nullptr, Bth0, Btl0, b_in, nullptr, h0h, h0l, N, K0, Kp0, HID, 1);

    // ---- GAT conv 1: hc1 = h0 @ W1 (pure-bf16 A path) ----
    gemm_mfma<1><<<dim3(HID / BN, gRows), blk, 0, stream>>>(
        nullptr, h0h, h0l, Bth1, Btl1, nullptr, hc1, nullptr, nullptr, N, HID, HID, HID, 0);
    attn_coeff<256><<<gNodeWave, blk, 0, stream>>>(hc1, as1, ad1, a_src, a_dst, N);
    gat_aggregate<256><<<gNodeWave, blk, 0, stream>>>(
        row_ptr, colv, hc1, a_src, a_dst, bias1, nullptr, h1h, h1l, N);

    // ---- GAT conv 2: hc2 = h1 @ W2 ----
    gemm_mfma<1><<<dim3(OUTF / BN, gRows), blk, 0, stream>>>(
        nullptr, h1h, h1l, Bth2, Btl2, nullptr, hc2, nullptr, nullptr, N, HID, HID, OUTF, 0);
    attn_coeff<128><<<gNodeWave, blk, 0, stream>>>(hc2, as2, ad2, a_src, a_dst, N);
    gat_aggregate<128><<<gNodeWave, blk, 0, stream>>>(
        row_ptr, colv, hc2, a_src, a_dst, bias2, out2, nullptr, nullptr, N);

    // ---- pool + head ----
    hipMemsetAsync(pooled, 0, 64 * 128 * 4 + 64 * 4, stream);
    pool_kernel<<<gPool, blk, 0, stream>>>(out2, batch, pooled, gcounts, N);
    head_kernel<<<dim3(16), blk, 0, stream>>>(pooled, gcounts, Wc, bc, Wf, bf, out);
}

// Round 8
// 884.891 us; speedup vs baseline: 1.1458x; 1.1458x over previous
//
#include <hip/hip_runtime.h>
#include <hip/hip_bf16.h>
#include <cstdint>

#define NEG_SLOPE 0.2f

typedef __attribute__((ext_vector_type(8))) short bf16x8;
typedef __attribute__((ext_vector_type(4))) float f32x4;

// ---------- bf16 helpers (manual RNE, bit-level) ----------
__device__ __forceinline__ unsigned short f2bf(float f) {
    unsigned u = __float_as_uint(f);
    unsigned r = (u + 0x7FFFu + ((u >> 16) & 1u)) >> 16;
    return (unsigned short)r;
}
__device__ __forceinline__ float bf2f(unsigned short h) {
    return __uint_as_float(((unsigned)h) << 16);
}
__device__ __forceinline__ void splitbf(float v, unsigned short& hi, unsigned short& lo) {
    hi = f2bf(v);
    lo = f2bf(v - bf2f(hi));
}

// 16-byte load that only assumes 4-byte alignment (rows with odd K, e.g. 773)
struct __attribute__((packed, aligned(4))) F4A4 { float x, y, z, w; };
__device__ __forceinline__ float4 load4_a4(const float* p) {
    F4A4 v = *reinterpret_cast<const F4A4*>(p);
    return make_float4(v.x, v.y, v.z, v.w);
}

// ---------- weight prep: W [K][M] fp32 -> Bt_hi/Bt_lo [M][Kp] bf16 (transposed, padded) ----------
__global__ __launch_bounds__(256) void convertB(
    const float* __restrict__ W, unsigned short* __restrict__ bth,
    unsigned short* __restrict__ btl, int K, int M, int Kp)
{
    int idx = blockIdx.x * 256 + threadIdx.x;
    if (idx >= M * Kp) return;
    int m = idx / Kp, k = idx % Kp;
    float v = (k < K) ? W[(size_t)k * M + m] : 0.0f;
    unsigned short h, l;
    splitbf(v, h, l);
    bth[idx] = h; btl[idx] = l;
}

// ---------- split-bf16 MFMA GEMM ----------
// APLANES=0: A fp32 [N][K], split in-kernel.  APLANES=1: A pre-split planes [N][Kp] bf16.
// 128x128 tile, 4 waves (2x2), 16x16x32 bf16 MFMA, 3 pairings (hh + lh + hl).
// NO register prefetch (round-6/7 spill lesson: regs held across barriers -> scratch).
// XOR 16B-chunk LDS swizzle (measured conflict-free, round 6).
#define BM 128
#define BN 128
#define BK 32
__device__ __forceinline__ int swz(int r, int c) { return c ^ ((r >> 1) & 3); }

template <int APLANES>
__global__ __launch_bounds__(256) void gemm_mfma(
    const float* __restrict__ Af, const unsigned short* __restrict__ Aph,
    const unsigned short* __restrict__ Apl,
    const unsigned short* __restrict__ Bth, const unsigned short* __restrict__ Btl,
    const float* __restrict__ bias, float* __restrict__ Cf,
    unsigned short* __restrict__ Ch, unsigned short* __restrict__ Cl,
    int N, int K, int Kp, int M, int dobias)
{
    __shared__ unsigned short sAh[BM][BK], sAl[BM][BK];
    __shared__ unsigned short sBh[BN][BK], sBl[BN][BK];
    const int tid = threadIdx.x;
    const int lane = tid & 63;
    const int wid = tid >> 6;
    const int wm = wid >> 1, wn = wid & 1;
    const int row0 = blockIdx.y * BM, col0 = blockIdx.x * BN;

    f32x4 acc[4][4];
    #pragma unroll
    for (int i = 0; i < 4; ++i)
        #pragma unroll
        for (int j = 0; j < 4; ++j)
            acc[i][j] = (f32x4)0.0f;

    for (int k0 = 0; k0 < Kp; k0 += BK) {
        // ---- stage A ----
        if constexpr (APLANES == 0) {
            #pragma unroll
            for (int i = 0; i < 4; ++i) {
                int flat = i * 256 + tid;
                int r = flat >> 3, ch = flat & 7;
                int gr = row0 + r, gk = k0 + ch * 4;
                float4 v = make_float4(0.f, 0.f, 0.f, 0.f);
                if (gr < N) {
                    const float* ap = Af + (size_t)gr * K + gk;
                    if (gk + 3 < K) {
                        v = load4_a4(ap);
                    } else {
                        if (gk + 0 < K) v.x = ap[0];
                        if (gk + 1 < K) v.y = ap[1];
                        if (gk + 2 < K) v.z = ap[2];
                        if (gk + 3 < K) v.w = ap[3];
                    }
                }
                unsigned short h0, h1, h2, h3, l0, l1, l2, l3;
                splitbf(v.x, h0, l0); splitbf(v.y, h1, l1);
                splitbf(v.z, h2, l2); splitbf(v.w, h3, l3);
                int cu = swz(r, ch >> 1) * 8 + (ch & 1) * 4;
                *reinterpret_cast<ushort4*>(&sAh[r][cu]) = make_ushort4(h0, h1, h2, h3);
                *reinterpret_cast<ushort4*>(&sAl[r][cu]) = make_ushort4(l0, l1, l2, l3);
            }
        } else {
            #pragma unroll
            for (int i = 0; i < 2; ++i) {
                int flat = i * 256 + tid;
                int r = flat >> 2, ch = flat & 3;
                int gr = row0 + r;
                uint4 vh = make_uint4(0, 0, 0, 0), vl = make_uint4(0, 0, 0, 0);
                if (gr < N) {
                    size_t goff = (size_t)gr * Kp + k0 + ch * 8;
                    vh = *reinterpret_cast<const uint4*>(Aph + goff);
                    vl = *reinterpret_cast<const uint4*>(Apl + goff);
                }
                int cu = swz(r, ch) * 8;
                *reinterpret_cast<uint4*>(&sAh[r][cu]) = vh;
                *reinterpret_cast<uint4*>(&sAl[r][cu]) = vl;
            }
        }
        // ---- stage B ----
        #pragma unroll
        for (int i = 0; i < 2; ++i) {
            int flat = i * 256 + tid;
            int r = flat >> 2, ch = flat & 3;
            size_t goff = (size_t)(col0 + r) * Kp + k0 + ch * 8;
            uint4 vh = *reinterpret_cast<const uint4*>(Bth + goff);
            uint4 vl = *reinterpret_cast<const uint4*>(Btl + goff);
            int cu = swz(r, ch) * 8;
            *reinterpret_cast<uint4*>(&sBh[r][cu]) = vh;
            *reinterpret_cast<uint4*>(&sBl[r][cu]) = vl;
        }
        __syncthreads();

        // ---- frags + MFMA from LDS ----
        const int g = lane >> 4;
        const int rA0 = wm * 64 + (lane & 15);
        const int rB0 = wn * 64 + (lane & 15);
        bf16x8 ah[4], al[4];
        #pragma unroll
        for (int m = 0; m < 4; ++m) {
            int rr = rA0 + m * 16;
            int cu = swz(rr, g) * 8;
            ah[m] = *reinterpret_cast<const bf16x8*>(&sAh[rr][cu]);
            al[m] = *reinterpret_cast<const bf16x8*>(&sAl[rr][cu]);
        }
        #pragma unroll
        for (int n = 0; n < 4; ++n) {
            int rr = rB0 + n * 16;
            int cu = swz(rr, g) * 8;
            bf16x8 bh = *reinterpret_cast<const bf16x8*>(&sBh[rr][cu]);
            bf16x8 bl = *reinterpret_cast<const bf16x8*>(&sBl[rr][cu]);
            #pragma unroll
            for (int m = 0; m < 4; ++m) {
                acc[m][n] = __builtin_amdgcn_mfma_f32_16x16x32_bf16(ah[m], bh, acc[m][n], 0, 0, 0);
                acc[m][n] = __builtin_amdgcn_mfma_f32_16x16x32_bf16(al[m], bh, acc[m][n], 0, 0, 0);
                acc[m][n] = __builtin_amdgcn_mfma_f32_16x16x32_bf16(ah[m], bl, acc[m][n], 0, 0, 0);
            }
        }
        __syncthreads();
    }

    // ---- C write: D layout col=lane&15, row=(lane>>4)*4+reg ----
    #pragma unroll
    for (int m = 0; m < 4; ++m) {
        #pragma unroll
        for (int n = 0; n < 4; ++n) {
            int col = col0 + wn * 64 + n * 16 + (lane & 15);
            #pragma unroll
            for (int r = 0; r < 4; ++r) {
                int row = row0 + wm * 64 + m * 16 + (lane >> 4) * 4 + r;
                if (row < N) {
                    float v = acc[m][n][r];
                    if (dobias) v = fmaxf(v + bias[col], 0.0f);
                    size_t o = (size_t)row * M + col;
                    if (Cf) Cf[o] = v;
                    if (Ch) {
                        unsigned short h, l;
                        splitbf(v, h, l);
                        Ch[o] = h; Cl[o] = l;
                    }
                }
            }
        }
    }
}

// ---------- per-node attention coefficients: a_src[n,h], a_dst[n,h] ----------
template <int F>   // F = H*C, H=4; one wave per node
__global__ __launch_bounds__(256) void attn_coeff(
    const float* __restrict__ h, const float* __restrict__ att_src,
    const float* __restrict__ att_dst, float* __restrict__ a_src,
    float* __restrict__ a_dst, int N)
{
    constexpr int VPT = F / 64;
    constexpr int C = F / 4;
    int wave = (blockIdx.x * blockDim.x + threadIdx.x) >> 6;
    int lane = threadIdx.x & 63;
    if (wave >= N) return;
    int j0 = lane * VPT;
    int hd = j0 / C;
    float ps = 0.f, pd = 0.f;
    #pragma unroll
    for (int t = 0; t < VPT; ++t) {
        int j = j0 + t;
        float v = h[(size_t)wave * F + j];
        int c = j - hd * C;
        ps += v * att_src[hd * C + c];
        pd += v * att_dst[hd * C + c];
    }
    #pragma unroll
    for (int off = 8; off >= 1; off >>= 1) {
        ps += __shfl_xor(ps, off, 64);
        pd += __shfl_xor(pd, off, 64);
    }
    if ((lane & 15) == 0) {
        a_src[wave * 4 + hd] = ps;
        a_dst[wave * 4 + hd] = pd;
    }
}

// ---------- CSR build: histogram ----------
__global__ __launch_bounds__(256) void hist_kernel(
    const int* __restrict__ ei, int* __restrict__ counts, int E, int Etot)
{
    int i = blockIdx.x * blockDim.x + threadIdx.x;
    if (i >= Etot) return;
    int d = (i < E) ? ei[E + i] : (i - E);
    atomicAdd(&counts[d], 1);
}

// ---------- CSR build: 3-stage exclusive scan -> row_ptr ----------
__global__ __launch_bounds__(256) void scan1_kernel(
    const int* __restrict__ counts, int* __restrict__ row_ptr,
    int* __restrict__ partials, int N)
{
    __shared__ int sh[256];
    int tid = threadIdx.x;
    int i = blockIdx.x * 256 + tid;
    int v = (i < N) ? counts[i] : 0;
    sh[tid] = v;
    __syncthreads();
    #pragma unroll
    for (int off = 1; off < 256; off <<= 1) {
        int t = (tid >= off) ? sh[tid - off] : 0;
        __syncthreads();
        sh[tid] += t;
        __syncthreads();
    }
    if (i < N) row_ptr[i + 1] = sh[tid];
    if (tid == 255) partials[blockIdx.x] = sh[255];
}

__global__ __launch_bounds__(256) void scan2_kernel(int* __restrict__ partials, int nb)
{
    __shared__ int sh[256];
    int tid = threadIdx.x;
    int v = (tid < nb) ? partials[tid] : 0;
    sh[tid] = v;
    __syncthreads();
    #pragma unroll
    for (int off = 1; off < 256; off <<= 1) {
        int t = (tid >= off) ? sh[tid - off] : 0;
        __syncthreads();
        sh[tid] += t;
        __syncthreads();
    }
    if (tid < nb) partials[tid] = sh[tid] - v;
}

__global__ __launch_bounds__(256) void scan3_kernel(
    int* __restrict__ row_ptr, const int* __restrict__ partials, int N)
{
    int i = blockIdx.x * 256 + threadIdx.x;
    if (i == 0) row_ptr[0] = 0;
    if (i < N) row_ptr[i + 1] += partials[i >> 8];
}

// ---------- CSR build: fill column (src) list ----------
__global__ __launch_bounds__(256) void fill_kernel(
    const int* __restrict__ ei, int* __restrict__ cursor,
    int* __restrict__ col, int E, int Etot)
{
    int i = blockIdx.x * blockDim.x + threadIdx.x;
    if (i >= Etot) return;
    int s, d;
    if (i < E) { s = ei[i]; d = ei[E + i]; } else { s = i - E; d = s; }
    int slot = atomicAdd(&cursor[d], 1);
    col[slot] = s;
}

// ---------- fused per-dst GAT aggregation: softmax + gather + bias + relu ----------
// Output: fp32 (outF) or pre-split hi/lo planes (outH/outL) for the next GEMM.
template <int F>   // one wave per destination node; C = F/4 per head
__global__ __launch_bounds__(256) void gat_aggregate(
    const int* __restrict__ row_ptr, const int* __restrict__ col,
    const float* __restrict__ h, const float* __restrict__ a_src,
    const float* __restrict__ a_dst, const float* __restrict__ bias,
    float* __restrict__ outF, unsigned short* __restrict__ outH,
    unsigned short* __restrict__ outL, int N)
{
    constexpr int VPT = F / 64;
    int wave = (blockIdx.x * blockDim.x + threadIdx.x) >> 6;
    int lane = threadIdx.x & 63;
    if (wave >= N) return;
    const int d = wave;
    const int start = row_ptr[d], end = row_ptr[d + 1];

    float4 adv = *reinterpret_cast<const float4*>(&a_dst[d * 4]);
    const float ad[4] = {adv.x, adv.y, adv.z, adv.w};

    float m[4] = {-1e30f, -1e30f, -1e30f, -1e30f};
    for (int j = start + lane; j < end; j += 64) {
        int s = col[j];
        float4 asv = *reinterpret_cast<const float4*>(&a_src[s * 4]);
        float ev[4] = {asv.x + ad[0], asv.y + ad[1], asv.z + ad[2], asv.w + ad[3]};
        #pragma unroll
        for (int hd = 0; hd < 4; ++hd) {
            float e = ev[hd];
            e = (e >= 0.f) ? e : NEG_SLOPE * e;
            m[hd] = fmaxf(m[hd], e);
        }
    }
    #pragma unroll
    for (int off = 32; off >= 1; off >>= 1) {
        #pragma unroll
        for (int hd = 0; hd < 4; ++hd)
            m[hd] = fmaxf(m[hd], __shfl_xor(m[hd], off, 64));
    }

    float den[4] = {0.f, 0.f, 0.f, 0.f};
    for (int j = start + lane; j < end; j += 64) {
        int s = col[j];
        float4 asv = *reinterpret_cast<const float4*>(&a_src[s * 4]);
        float ev[4] = {asv.x + ad[0], asv.y + ad[1], asv.z + ad[2], asv.w + ad[3]};
        #pragma unroll
        for (int hd = 0; hd < 4; ++hd) {
            float e = ev[hd];
            e = (e >= 0.f) ? e : NEG_SLOPE * e;
            den[hd] += __expf(e - m[hd]);
        }
    }
    #pragma unroll
    for (int off = 32; off >= 1; off >>= 1) {
        #pragma unroll
        for (int hd = 0; hd < 4; ++hd)
            den[hd] += __shfl_xor(den[hd], off, 64);
    }

    const int hd_l = lane >> 4;
    const float mm = m[hd_l];
    const float iv = 1.0f / (den[hd_l] + 1e-16f);
    const float adh = ad[hd_l];
    float acc[VPT] = {};
    for (int j = start; j < end; ++j) {
        int s = col[j];
        float e = a_src[s * 4 + hd_l] + adh;
        e = (e >= 0.f) ? e : NEG_SLOPE * e;
        float alpha = __expf(e - mm) * iv;
        if constexpr (VPT == 4) {
            float4 hv = *reinterpret_cast<const float4*>(&h[(size_t)s * F + lane * 4]);
            acc[0] += hv.x * alpha; acc[1] += hv.y * alpha;
            acc[2] += hv.z * alpha; acc[3] += hv.w * alpha;
        } else {
            float2 hv = *reinterpret_cast<const float2*>(&h[(size_t)s * F + lane * 2]);
            acc[0] += hv.x * alpha; acc[1] += hv.y * alpha;
        }
    }
    #pragma unroll
    for (int t = 0; t < VPT; ++t) {
        int j = lane * VPT + t;
        float v = fmaxf(acc[t] + bias[j], 0.0f);
        size_t o = (size_t)d * F + j;
        if (outF) {
            outF[o] = v;
        } else {
            unsigned short hh, ll;
            splitbf(v, hh, ll);
            outH[o] = hh; outL[o] = ll;
        }
    }
}

// ---------- mean pool: batch is SORTED -> register accumulate, flush on graph change ----------
#define POOL_RPW 64
__global__ __launch_bounds__(256) void pool_kernel(
    const float* __restrict__ h2, const int* __restrict__ batch,
    float* __restrict__ pooled, float* __restrict__ counts, int N)
{
    int wave = (blockIdx.x * blockDim.x + threadIdx.x) >> 6;
    int lane = threadIdx.x & 63;
    int r0 = wave * POOL_RPW;
    if (r0 >= N) return;
    int r1 = min(r0 + POOL_RPW, N);
    int cur_g = batch[r0];
    float a0 = 0.f, a1 = 0.f, cnt = 0.f;
    for (int r = r0; r < r1; ++r) {
        int g = batch[r];
        if (g != cur_g) {
            atomicAdd(&pooled[cur_g * 128 + lane * 2 + 0], a0);
            atomicAdd(&pooled[cur_g * 128 + lane * 2 + 1], a1);
            if (lane == 0) atomicAdd(&counts[cur_g], cnt);
            a0 = a1 = cnt = 0.f;
            cur_g = g;
        }
        float2 hv = *reinterpret_cast<const float2*>(&h2[(size_t)r * 128 + lane * 2]);
        a0 += hv.x; a1 += hv.y; cnt += 1.f;
    }
    atomicAdd(&pooled[cur_g * 128 + lane * 2 + 0], a0);
    atomicAdd(&pooled[cur_g * 128 + lane * 2 + 1], a1);
    if (lane == 0) atomicAdd(&counts[cur_g], cnt);
}

// ---------- classifier head: one wave per graph ----------
__global__ __launch_bounds__(256) void head_kernel(
    const float* __restrict__ pooled, const float* __restrict__ counts,
    const float* __restrict__ Wc, const float* __restrict__ bc,
    const float* __restrict__ Wf, const float* __restrict__ bf,
    float* __restrict__ out)
{
    int wave = (blockIdx.x * blockDim.x + threadIdx.x) >> 6;
    int lane = threadIdx.x & 63;
    if (wave >= 64) return;
    float inv = 1.0f / fmaxf(counts[wave], 1.0f);
    float p0 = pooled[wave * 128 + lane] * inv;
    float p1 = pooled[wave * 128 + 64 + lane] * inv;
    float a0 = p0 * Wc[lane * 2 + 0] + p1 * Wc[(lane + 64) * 2 + 0];
    float a1 = p0 * Wc[lane * 2 + 1] + p1 * Wc[(lane + 64) * 2 + 1];
    float ac = p0 * Wf[lane] + p1 * Wf[lane + 64];
    #pragma unroll
    for (int off = 32; off >= 1; off >>= 1) {
        a0 += __shfl_xor(a0, off, 64);
        a1 += __shfl_xor(a1, off, 64);
        ac += __shfl_xor(ac, off, 64);
    }
    if (lane == 0) {
        out[wave * 2 + 0] = a0 + bc[0];
        out[wave * 2 + 1] = a1 + bc[1];
        out[128 + wave] = 1.0f / (1.0f + __expf(-(ac + bf[0])));
    }
}

extern "C" void kernel_launch(void* const* d_in, const int* in_sizes, int n_in,
                              void* d_out, int out_size, void* d_ws, size_t ws_size,
                              hipStream_t stream)
{
    const float* x     = (const float*)d_in[0];
    const int*   ei    = (const int*)d_in[1];
    const int*   batch = (const int*)d_in[2];
    const float* W_in  = (const float*)d_in[3];
    const float* b_in  = (const float*)d_in[4];
    const float* W1    = (const float*)d_in[5];
    const float* as1   = (const float*)d_in[6];
    const float* ad1   = (const float*)d_in[7];
    const float* bias1 = (const float*)d_in[8];
    const float* W2    = (const float*)d_in[9];
    const float* as2   = (const float*)d_in[10];
    const float* ad2   = (const float*)d_in[11];
    const float* bias2 = (const float*)d_in[12];
    const float* Wc    = (const float*)d_in[13];
    const float* bc    = (const float*)d_in[14];
    const float* Wf    = (const float*)d_in[15];
    const float* bf    = (const float*)d_in[16];
    float* out = (float*)d_out;

    const int N    = in_sizes[2];          // 50000
    const int E    = in_sizes[1] / 2;      // 800000
    const int K0   = in_sizes[0] / N;      // 773
    const int Etot = E + N;
    const int HID = 256, OUTF = 128;
    const int Kp0 = ((K0 + 31) / 32) * 32; // 800
    const int nb  = (N + 255) / 256;

    char* ws = (char*)d_ws;
    size_t off = 0;
    auto alloc = [&](size_t bytes) -> void* {
        void* p = ws + off;
        off = (off + bytes + 255) & ~(size_t)255;
        return p;
    };
    // P0: h0 hi/lo planes (layer-1 GEMM input), later reused for h1 planes
    unsigned short* P0 = (unsigned short*)alloc((size_t)N * HID * 2 * 2);
    // P1: hc1 fp32, later hc2 + out2
    float* P1      = (float*)alloc((size_t)N * HID * 4);
    float* a_src   = (float*)alloc((size_t)N * 4 * 4);
    float* a_dst   = (float*)alloc((size_t)N * 4 * 4);
    int*   counts  = (int*)alloc((size_t)(N + 1) * 4);
    int*   row_ptr = (int*)alloc((size_t)(N + 1) * 4);
    int*   cursor  = (int*)alloc((size_t)N * 4);
    int*   colv    = (int*)alloc((size_t)Etot * 4);
    int*   partials= (int*)alloc(256 * 4);
    float* pooled  = (float*)alloc(64 * 128 * 4);
    float* gcounts = (float*)alloc(64 * 4);
    unsigned short* Bth0 = (unsigned short*)alloc((size_t)HID * Kp0 * 2);
    unsigned short* Btl0 = (unsigned short*)alloc((size_t)HID * Kp0 * 2);
    unsigned short* Bth1 = (unsigned short*)alloc((size_t)HID * HID * 2);
    unsigned short* Btl1 = (unsigned short*)alloc((size_t)HID * HID * 2);
    unsigned short* Bth2 = (unsigned short*)alloc((size_t)OUTF * HID * 2);
    unsigned short* Btl2 = (unsigned short*)alloc((size_t)OUTF * HID * 2);
    (void)ws_size; (void)n_in; (void)out_size;

    unsigned short* h0h = P0;
    unsigned short* h0l = P0 + (size_t)N * HID;
    unsigned short* h1h = P0;                       // reuse after gemm2
    unsigned short* h1l = P0 + (size_t)N * HID;
    float* hc1  = P1;
    float* hc2  = P1;                               // reuse after agg1
    float* out2 = P1 + (size_t)N * OUTF;

    dim3 blk(256);
    dim3 gEdge((Etot + 255) / 256);
    dim3 gNodeWave((N + 3) / 4);
    dim3 gNodeTh((N + 255) / 256);
    dim3 gPool(((N + POOL_RPW - 1) / POOL_RPW + 3) / 4);
    const int gRows = (N + BM - 1) / BM;

    // ---- weight split/transpose (tiny) ----
    convertB<<<dim3((HID * Kp0 + 255) / 256), blk, 0, stream>>>(W_in, Bth0, Btl0, K0, HID, Kp0);
    convertB<<<dim3((HID * HID + 255) / 256), blk, 0, stream>>>(W1, Bth1, Btl1, HID, HID, HID);
    convertB<<<dim3((OUTF * HID + 255) / 256), blk, 0, stream>>>(W2, Bth2, Btl2, HID, OUTF, HID);

    // ---- CSR build (reused by both GAT layers) ----
    hipMemsetAsync(counts, 0, (size_t)(N + 1) * 4, stream);
    hist_kernel<<<gEdge, blk, 0, stream>>>(ei, counts, E, Etot);
    scan1_kernel<<<dim3(nb), blk, 0, stream>>>(counts, row_ptr, partials, N);
    scan2_kernel<<<dim3(1), blk, 0, stream>>>(partials, nb);
    scan3_kernel<<<gNodeTh, blk, 0, stream>>>(row_ptr, partials, N);
    hipMemcpyAsync(cursor, row_ptr, (size_t)N * 4, hipMemcpyDeviceToDevice, stream);
    fill_kernel<<<gEdge, blk, 0, stream>>>(ei, cursor, colv, E, Etot);

    // ---- input projection: h0 = relu(x @ W_in + b_in), emitted as split planes ----
    gemm_mfma<0><<<dim3(HID / BN, gRows), blk, 0, stream>>>(
        x, nullptr, nullptr, Bth0, Btl0, b_in, nullptr, h0h, h0l, N, K0, Kp0, HID, 1);

    // ---- GAT conv 1: hc1 = h0 @ W1 (pure-bf16 A path) ----
    gemm_mfma<1><<<dim3(HID / BN, gRows), blk, 0, stream>>>(
        nullptr, h0h, h0l, Bth1, Btl1, nullptr, hc1, nullptr, nullptr, N, HID, HID, HID, 0);
    attn_coeff<256><<<gNodeWave, blk, 0, stream>>>(hc1, as1, ad1, a_src, a_dst, N);
    gat_aggregate<256><<<gNodeWave, blk, 0, stream>>>(
        row_ptr, colv, hc1, a_src, a_dst, bias1, nullptr, h1h, h1l, N);

    // ---- GAT conv 2: hc2 = h1 @ W2 ----
    gemm_mfma<1><<<dim3(OUTF / BN, gRows), blk, 0, stream>>>(
        nullptr, h1h, h1l, Bth2, Btl2, nullptr, hc2, nullptr, nullptr, N, HID, HID, OUTF, 0);
    attn_coeff<128><<<gNodeWave, blk, 0, stream>>>(hc2, as2, ad2, a_src, a_dst, N);
    gat_aggregate<128><<<gNodeWave, blk, 0, stream>>>(
        row_ptr, colv, hc2, a_src, a_dst, bias2, out2, nullptr, nullptr, N);

    // ---- pool + head ----
    hipMemsetAsync(pooled, 0, 64 * 128 * 4 + 64 * 4, stream);
    pool_kernel<<<gPool, blk, 0, stream>>>(out2, batch, pooled, gcounts, N);
    head_kernel<<<dim3(16), blk, 0, stream>>>(pooled, gcounts, Wc, bc, Wf, bf, out);
}